// Round 2
// baseline (214.583 us; speedup 1.0000x reference)
//
#include <hip/hip_runtime.h>
#include <hip/hip_bf16.h>
#include <stdint.h>

typedef unsigned short u16;
typedef __attribute__((ext_vector_type(8))) short short8;
typedef __attribute__((ext_vector_type(4))) float f32x4;
typedef __attribute__((ext_vector_type(4))) u16 u16x4;

#define S_LEN 2048
#define D_DIM 1024
#define NBATCH 4
#define BM 128
#define BN 128
#define BK 32

enum { MODE_QK = 0, MODE_V = 1, MODE_SC = 2, MODE_PV = 3 };

__device__ inline u16 f2bf(float f) {
  uint32_t u = __float_as_uint(f);
  uint32_t r = (u + 0x7fffu + ((u >> 16) & 1u)) >> 16;
  return (u16)r;
}

__global__ __launch_bounds__(256) void cast_f32_bf16(
    const float* __restrict__ in, u16* __restrict__ out, int n) {
  int i = (blockIdx.x * blockDim.x + threadIdx.x) * 4;
  int stride = gridDim.x * blockDim.x * 4;
  for (; i < n; i += stride) {
    f32x4 v = *reinterpret_cast<const f32x4*>(in + i);
    u16x4 o;
    o[0] = f2bf(v[0]); o[1] = f2bf(v[1]); o[2] = f2bf(v[2]); o[3] = f2bf(v[3]);
    *reinterpret_cast<u16x4*>(out + i) = o;
  }
}

// C = A (bf16 [M,K]) * B^T (bf16 [N,K]) ; lda = ldb = K.
// MODE_QK: C bf16 [M,N] rowmajor.  MODE_V: C bf16 transposed-batched Vt[b][n][s].
// MODE_SC: C f32, triangular block grid.  MODE_PV: C f32, K-loop truncated at diagonal.
template <int MODE>
__global__ __launch_bounds__(256, 2) void gemm_bt(
    const u16* __restrict__ A, const u16* __restrict__ B, void* __restrict__ C,
    int M, int N, int K, long strideAb, long strideBb, long strideCb, int ldc) {
  __shared__ u16 As[2][BM * BK];
  __shared__ u16 Bs[2][BN * BK];

  const int bz = blockIdx.z;
  const u16* Ab = A + (long)bz * strideAb;
  const u16* Bb = B + (long)bz * strideBb;

  int br, bc;
  if (MODE == MODE_SC) {
    int t = blockIdx.x;
    int r = (int)((sqrtf(8.0f * (float)t + 1.0f) - 1.0f) * 0.5f);
    while ((r + 1) * (r + 2) / 2 <= t) ++r;
    while (r * (r + 1) / 2 > t) --r;
    br = r;
    bc = t - r * (r + 1) / 2;
  } else {
    br = blockIdx.x;
    bc = blockIdx.y;
  }

  const int rowBase = br * BM;
  const int colBase = bc * BN;
  int nkt = (MODE == MODE_PV) ? (br + 1) * (BM / BK) : (K / BK);

  const int tid = threadIdx.x;
  const int lane = tid & 63;
  const int wave = tid >> 6;
  const int wr = wave >> 1, wc = wave & 1;

  f32x4 acc[4][4];
#pragma unroll
  for (int i = 0; i < 4; i++)
#pragma unroll
    for (int j = 0; j < 4; j++) acc[i][j] = f32x4{0.f, 0.f, 0.f, 0.f};

  const int srow = tid >> 2;          // 0..63 (first half of tile rows)
  const int skc = (tid & 3) * 8;      // 0,8,16,24

  // Stage the FULL 128x32 bf16 tile (8 KB): 2 x (256 lanes x 16 B) per matrix.
  auto stage = [&](int buf, int kt) {
    const u16* ga = Ab + (long)(rowBase + srow) * K + kt * BK + skc;
    const u16* gb = Bb + (long)(colBase + srow) * K + kt * BK + skc;
    __builtin_amdgcn_global_load_lds(
        (const __attribute__((address_space(1))) void*)ga,
        (__attribute__((address_space(3))) void*)(&As[buf][tid * 8]), 16, 0, 0);
    __builtin_amdgcn_global_load_lds(
        (const __attribute__((address_space(1))) void*)(ga + (long)64 * K),
        (__attribute__((address_space(3))) void*)(&As[buf][64 * BK + tid * 8]), 16, 0, 0);
    __builtin_amdgcn_global_load_lds(
        (const __attribute__((address_space(1))) void*)gb,
        (__attribute__((address_space(3))) void*)(&Bs[buf][tid * 8]), 16, 0, 0);
    __builtin_amdgcn_global_load_lds(
        (const __attribute__((address_space(1))) void*)(gb + (long)64 * K),
        (__attribute__((address_space(3))) void*)(&Bs[buf][64 * BK + tid * 8]), 16, 0, 0);
  };

  stage(0, 0);
  int cur = 0;
  for (int kt = 0; kt < nkt; ++kt) {
    if (kt + 1 < nkt) stage(cur ^ 1, kt + 1);
    __syncthreads();
    short8 af[4], bf[4];
#pragma unroll
    for (int i = 0; i < 4; i++)
      af[i] = *reinterpret_cast<const short8*>(
          &As[cur][(wr * 64 + i * 16 + (lane & 15)) * BK + (lane >> 4) * 8]);
#pragma unroll
    for (int j = 0; j < 4; j++)
      bf[j] = *reinterpret_cast<const short8*>(
          &Bs[cur][(wc * 64 + j * 16 + (lane & 15)) * BK + (lane >> 4) * 8]);
#pragma unroll
    for (int i = 0; i < 4; i++)
#pragma unroll
      for (int j = 0; j < 4; j++)
        acc[i][j] = __builtin_amdgcn_mfma_f32_16x16x32_bf16(af[i], bf[j], acc[i][j], 0, 0, 0);
    __syncthreads();
    cur ^= 1;
  }

  const int lr = (lane >> 4) * 4;
  const int lc = lane & 15;

  if (MODE == MODE_QK) {
    u16* Cb = (u16*)C + (long)bz * strideCb;
#pragma unroll
    for (int i = 0; i < 4; i++) {
      int r0 = rowBase + wr * 64 + i * 16 + lr;
#pragma unroll
      for (int j = 0; j < 4; j++) {
        int c0 = colBase + wc * 64 + j * 16 + lc;
#pragma unroll
        for (int q = 0; q < 4; q++) Cb[(long)(r0 + q) * ldc + c0] = f2bf(acc[i][j][q]);
      }
    }
  } else if (MODE == MODE_V) {
    u16* Cb = (u16*)C;  // Vt [NBATCH][D_DIM][S_LEN]
#pragma unroll
    for (int i = 0; i < 4; i++) {
      int m0 = rowBase + wr * 64 + i * 16 + lr;
      int b = m0 >> 11, s0 = m0 & (S_LEN - 1);
#pragma unroll
      for (int j = 0; j < 4; j++) {
        int h = colBase + wc * 64 + j * 16 + lc;
        u16x4 o;
        o[0] = f2bf(acc[i][j][0]); o[1] = f2bf(acc[i][j][1]);
        o[2] = f2bf(acc[i][j][2]); o[3] = f2bf(acc[i][j][3]);
        *reinterpret_cast<u16x4*>(Cb + ((long)b * D_DIM + h) * S_LEN + s0) = o;
      }
    }
  } else {
    float* Cb = (float*)C + (long)bz * strideCb;
#pragma unroll
    for (int i = 0; i < 4; i++) {
      int r0 = rowBase + wr * 64 + i * 16 + lr;
#pragma unroll
      for (int j = 0; j < 4; j++) {
        int c0 = colBase + wc * 64 + j * 16 + lc;
#pragma unroll
        for (int q = 0; q < 4; q++) Cb[(long)(r0 + q) * ldc + c0] = acc[i][j][q];
      }
    }
  }
}

// one block per row: masked scaled softmax over cols [0, i], zero-fill to 128-boundary.
__global__ __launch_bounds__(256) void softmax_causal(
    const float* __restrict__ scores, u16* __restrict__ P, long strideSb, long stridePb) {
  const int b = blockIdx.z;
  const int i = blockIdx.x;
  const float* srow = scores + (long)b * strideSb + (long)i * S_LEN;
  u16* prow = P + (long)b * stridePb + (long)i * S_LEN;
  const int W = ((i >> 7) + 1) << 7;  // multiple of 128
  const int tid = threadIdx.x;
  const int lane = tid & 63;
  const int wave = tid >> 6;

  f32x4 v[2];
  int nc = 0;
  float lmax = -1e30f;
  for (int j = tid * 4; j < W; j += 1024) {
    f32x4 x = *reinterpret_cast<const f32x4*>(srow + j);
#pragma unroll
    for (int q = 0; q < 4; q++) {
      x[q] = (j + q <= i) ? x[q] * 0.03125f : -1e30f;
      lmax = fmaxf(lmax, x[q]);
    }
    v[nc++] = x;
  }
#pragma unroll
  for (int off = 32; off; off >>= 1) lmax = fmaxf(lmax, __shfl_xor(lmax, off));
  __shared__ float redm[4], reds[4];
  if (lane == 0) redm[wave] = lmax;
  __syncthreads();
  const float m = fmaxf(fmaxf(redm[0], redm[1]), fmaxf(redm[2], redm[3]));

  float lsum = 0.f;
  int c = 0;
  for (int j = tid * 4; j < W; j += 1024, ++c) {
#pragma unroll
    for (int q = 0; q < 4; q++) {
      float p = __expf(v[c][q] - m);
      v[c][q] = p;
      lsum += p;
    }
  }
#pragma unroll
  for (int off = 32; off; off >>= 1) lsum += __shfl_xor(lsum, off);
  if (lane == 0) reds[wave] = lsum;
  __syncthreads();
  const float inv = 1.f / (reds[0] + reds[1] + reds[2] + reds[3]);

  c = 0;
  for (int j = tid * 4; j < W; j += 1024, ++c) {
    u16x4 o;
#pragma unroll
    for (int q = 0; q < 4; q++) o[q] = f2bf(v[c][q] * inv);
    *reinterpret_cast<u16x4*>(prow + j) = o;
  }
}

extern "C" void kernel_launch(void* const* d_in, const int* in_sizes, int n_in,
                              void* d_out, int out_size, void* d_ws, size_t ws_size,
                              hipStream_t stream) {
  const float* x = (const float*)d_in[0];
  const float* Wq = (const float*)d_in[1];
  const float* Wk = (const float*)d_in[2];
  const float* Wv = (const float*)d_in[3];
  float* out = (float*)d_out;

  const size_t SD = (size_t)S_LEN * D_DIM;  // 2,097,152
  const size_t SS = (size_t)S_LEN * S_LEN;  // 4,194,304
  const size_t DD = (size_t)D_DIM * D_DIM;

  size_t off = 0;
  char* ws = (char*)d_ws;
  auto alloc = [&](size_t bytes) -> char* {
    char* p = ws + off;
    off += (bytes + 255) & ~(size_t)255;
    return p;
  };
  u16* xb = (u16*)alloc(NBATCH * SD * 2);
  u16* Wqb = (u16*)alloc(DD * 2);
  u16* Wkb = (u16*)alloc(DD * 2);
  u16* Wvb = (u16*)alloc(DD * 2);
  u16* Qb = (u16*)alloc(NBATCH * SD * 2);
  u16* Kb = (u16*)alloc(NBATCH * SD * 2);
  u16* Vt = (u16*)alloc(NBATCH * SD * 2);
  size_t need_full = off + ((NBATCH * SS * 4 + 255) & ~(size_t)255) +
                     ((NBATCH * SS * 2 + 255) & ~(size_t)255);
  const int nbpar = (ws_size >= need_full) ? NBATCH : 1;
  float* scores = (float*)alloc((size_t)nbpar * SS * 4);
  u16* P = (u16*)alloc((size_t)nbpar * SS * 2);

  // casts
  cast_f32_bf16<<<2048, 256, 0, stream>>>(x, xb, (int)(NBATCH * SD));
  cast_f32_bf16<<<512, 256, 0, stream>>>(Wq, Wqb, (int)DD);
  cast_f32_bf16<<<512, 256, 0, stream>>>(Wk, Wkb, (int)DD);
  cast_f32_bf16<<<512, 256, 0, stream>>>(Wv, Wvb, (int)DD);

  // projections: M = B*S = 8192, N = D = 1024, K = D = 1024
  dim3 gp((NBATCH * S_LEN) / BM, D_DIM / BN, 1);
  gemm_bt<MODE_QK><<<gp, 256, 0, stream>>>(xb, Wqb, Qb, NBATCH * S_LEN, D_DIM, D_DIM, 0, 0, 0, D_DIM);
  gemm_bt<MODE_QK><<<gp, 256, 0, stream>>>(xb, Wkb, Kb, NBATCH * S_LEN, D_DIM, D_DIM, 0, 0, 0, D_DIM);
  gemm_bt<MODE_V><<<gp, 256, 0, stream>>>(xb, Wvb, Vt, NBATCH * S_LEN, D_DIM, D_DIM, 0, 0, 0, D_DIM);

  const int ntri = (S_LEN / BM) * (S_LEN / BM + 1) / 2;  // 136
  if (nbpar == NBATCH) {
    gemm_bt<MODE_SC><<<dim3(ntri, 1, NBATCH), 256, 0, stream>>>(
        Qb, Kb, scores, S_LEN, S_LEN, D_DIM, (long)SD, (long)SD, (long)SS, S_LEN);
    softmax_causal<<<dim3(S_LEN, 1, NBATCH), 256, 0, stream>>>(scores, P, (long)SS, (long)SS);
    gemm_bt<MODE_PV><<<dim3(S_LEN / BM, D_DIM / BN, NBATCH), 256, 0, stream>>>(
        P, Vt, out, S_LEN, D_DIM, S_LEN, (long)SS, (long)SD, (long)SD, D_DIM);
  } else {
    for (int b = 0; b < NBATCH; ++b) {
      gemm_bt<MODE_SC><<<dim3(ntri, 1, 1), 256, 0, stream>>>(
          Qb + b * SD, Kb + b * SD, scores, S_LEN, S_LEN, D_DIM, 0, 0, 0, S_LEN);
      softmax_causal<<<dim3(S_LEN, 1, 1), 256, 0, stream>>>(scores, P, 0, 0);
      gemm_bt<MODE_PV><<<dim3(S_LEN / BM, D_DIM / BN, 1), 256, 0, stream>>>(
          P, Vt + b * SD, out + b * SD, S_LEN, D_DIM, S_LEN, 0, 0, 0, D_DIM);
    }
  }
}

// Round 3
// 206.935 us; speedup vs baseline: 1.0370x; 1.0370x over previous
//
#include <hip/hip_runtime.h>
#include <hip/hip_bf16.h>
#include <stdint.h>

typedef unsigned short u16;
typedef __attribute__((ext_vector_type(8))) short short8;
typedef __attribute__((ext_vector_type(4))) float f32x4;
typedef __attribute__((ext_vector_type(4))) u16 u16x4;

#define S_LEN 2048
#define D_DIM 1024
#define NBATCH 4
#define BM 128
#define BN 128
#define BK 32

enum { MODE_QKV = 0, MODE_SC = 2, MODE_PV = 3 };

__device__ inline u16 f2bf(float f) {
  uint32_t u = __float_as_uint(f);
  uint32_t r = (u + 0x7fffu + ((u >> 16) & 1u)) >> 16;
  return (u16)r;
}

__global__ __launch_bounds__(256) void cast_f32_bf16(
    const float* __restrict__ in, u16* __restrict__ out, int n) {
  int i = (blockIdx.x * blockDim.x + threadIdx.x) * 4;
  int stride = gridDim.x * blockDim.x * 4;
  for (; i < n; i += stride) {
    f32x4 v = *reinterpret_cast<const f32x4*>(in + i);
    u16x4 o;
    o[0] = f2bf(v[0]); o[1] = f2bf(v[1]); o[2] = f2bf(v[2]); o[3] = f2bf(v[3]);
    *reinterpret_cast<u16x4*>(out + i) = o;
  }
}

// C = A (bf16 [M,K]) * B^T (bf16 [N,K]) ; lda = ldb = K.
// MODE_QKV: B = [Wq;Wk;Wv] (N=3072); C base = Qb; K at +seg, Vt (transposed) at +2*seg.
// MODE_SC: C f32, triangular block grid.  MODE_PV: C f32, K-loop truncated at diagonal,
//          br remapped heavy/light-interleaved for load balance.
template <int MODE>
__global__ __launch_bounds__(256, 2) void gemm_bt(
    const u16* __restrict__ A, const u16* __restrict__ B, void* __restrict__ C,
    int M, int N, int K, long strideAb, long strideBb, long strideCb, int ldc) {
  __shared__ u16 As[2][BM * BK];
  __shared__ u16 Bs[2][BN * BK];

  const int bz = blockIdx.z;
  const u16* Ab = A + (long)bz * strideAb;
  const u16* Bb = B + (long)bz * strideBb;

  int br, bc;
  if (MODE == MODE_SC) {
    int t = blockIdx.x;
    int r = (int)((sqrtf(8.0f * (float)t + 1.0f) - 1.0f) * 0.5f);
    while ((r + 1) * (r + 2) / 2 <= t) ++r;
    while (r * (r + 1) / 2 > t) --r;
    br = r;
    bc = t - r * (r + 1) / 2;
  } else if (MODE == MODE_PV) {
    // heavy/light interleave: x=0 -> br 15 (heaviest), x=1 -> br 0, x=2 -> br 14, ...
    int xr = blockIdx.x;
    int nt = gridDim.x;
    br = (xr & 1) ? (xr >> 1) : (nt - 1 - (xr >> 1));
    bc = blockIdx.y;
  } else {
    // MODE_QKV: XCD-aware swizzle over the flat 64x24 grid (1536 % 8 == 0).
    int lin = blockIdx.y * gridDim.x + blockIdx.x;
    int nwg = gridDim.x * gridDim.y;
    int cpx = nwg >> 3;
    int swz = (lin & 7) * cpx + (lin >> 3);
    br = swz % gridDim.x;
    bc = swz / gridDim.x;
  }

  const int rowBase = br * BM;
  const int colBase = bc * BN;
  int nkt = (MODE == MODE_PV) ? (br + 1) * (BM / BK) : (K / BK);

  const int tid = threadIdx.x;
  const int lane = tid & 63;
  const int wave = tid >> 6;
  const int wr = wave >> 1, wc = wave & 1;

  f32x4 acc[4][4];
#pragma unroll
  for (int i = 0; i < 4; i++)
#pragma unroll
    for (int j = 0; j < 4; j++) acc[i][j] = f32x4{0.f, 0.f, 0.f, 0.f};

  const int srow = tid >> 2;          // 0..63
  const int skc = (tid & 3) * 8;      // 0,8,16,24

  // Stage the FULL 128x32 bf16 tile (8 KB): 2 x (256 lanes x 16 B) per matrix.
  auto stage = [&](int buf, int kt) {
    const u16* ga = Ab + (long)(rowBase + srow) * K + kt * BK + skc;
    const u16* gb = Bb + (long)(colBase + srow) * K + kt * BK + skc;
    __builtin_amdgcn_global_load_lds(
        (const __attribute__((address_space(1))) void*)ga,
        (__attribute__((address_space(3))) void*)(&As[buf][tid * 8]), 16, 0, 0);
    __builtin_amdgcn_global_load_lds(
        (const __attribute__((address_space(1))) void*)(ga + (long)64 * K),
        (__attribute__((address_space(3))) void*)(&As[buf][64 * BK + tid * 8]), 16, 0, 0);
    __builtin_amdgcn_global_load_lds(
        (const __attribute__((address_space(1))) void*)gb,
        (__attribute__((address_space(3))) void*)(&Bs[buf][tid * 8]), 16, 0, 0);
    __builtin_amdgcn_global_load_lds(
        (const __attribute__((address_space(1))) void*)(gb + (long)64 * K),
        (__attribute__((address_space(3))) void*)(&Bs[buf][64 * BK + tid * 8]), 16, 0, 0);
  };

  stage(0, 0);
  int cur = 0;
  for (int kt = 0; kt < nkt; ++kt) {
    if (kt + 1 < nkt) stage(cur ^ 1, kt + 1);
    __syncthreads();
    short8 af[4], bf[4];
#pragma unroll
    for (int i = 0; i < 4; i++)
      af[i] = *reinterpret_cast<const short8*>(
          &As[cur][(wr * 64 + i * 16 + (lane & 15)) * BK + (lane >> 4) * 8]);
#pragma unroll
    for (int j = 0; j < 4; j++)
      bf[j] = *reinterpret_cast<const short8*>(
          &Bs[cur][(wc * 64 + j * 16 + (lane & 15)) * BK + (lane >> 4) * 8]);
#pragma unroll
    for (int i = 0; i < 4; i++)
#pragma unroll
      for (int j = 0; j < 4; j++)
        acc[i][j] = __builtin_amdgcn_mfma_f32_16x16x32_bf16(af[i], bf[j], acc[i][j], 0, 0, 0);
    __syncthreads();
    cur ^= 1;
  }

  const int lr = (lane >> 4) * 4;
  const int lc = lane & 15;

  if (MODE == MODE_QKV) {
    u16* Cb = (u16*)C;  // Qb base; Kb at +seg; Vt at +2*seg
    const long seg = (long)NBATCH * S_LEN * D_DIM;
    const int segi = colBase >> 10;  // 0=Q, 1=K, 2=V (BN=128 divides 1024)
    if (segi < 2) {
      u16* dst = Cb + (long)segi * seg;
      const int hb = colBase & 1023;
#pragma unroll
      for (int i = 0; i < 4; i++) {
        int r0 = rowBase + wr * 64 + i * 16 + lr;
#pragma unroll
        for (int j = 0; j < 4; j++) {
          int c0 = hb + wc * 64 + j * 16 + lc;
#pragma unroll
          for (int q = 0; q < 4; q++) dst[(long)(r0 + q) * D_DIM + c0] = f2bf(acc[i][j][q]);
        }
      }
    } else {
      u16* dst = Cb + 2 * seg;  // Vt [NBATCH][D_DIM][S_LEN]
      const int hb = colBase & 1023;
#pragma unroll
      for (int i = 0; i < 4; i++) {
        int m0 = rowBase + wr * 64 + i * 16 + lr;
        int b = m0 >> 11, s0 = m0 & (S_LEN - 1);
#pragma unroll
        for (int j = 0; j < 4; j++) {
          int h = hb + wc * 64 + j * 16 + lc;
          u16x4 o;
          o[0] = f2bf(acc[i][j][0]); o[1] = f2bf(acc[i][j][1]);
          o[2] = f2bf(acc[i][j][2]); o[3] = f2bf(acc[i][j][3]);
          *reinterpret_cast<u16x4*>(dst + ((long)b * D_DIM + h) * S_LEN + s0) = o;
        }
      }
    }
  } else {
    float* Cb = (float*)C + (long)bz * strideCb;
#pragma unroll
    for (int i = 0; i < 4; i++) {
      int r0 = rowBase + wr * 64 + i * 16 + lr;
#pragma unroll
      for (int j = 0; j < 4; j++) {
        int c0 = colBase + wc * 64 + j * 16 + lc;
#pragma unroll
        for (int q = 0; q < 4; q++) Cb[(long)(r0 + q) * ldc + c0] = acc[i][j][q];
      }
    }
  }
}

// one block per row: masked scaled softmax over cols [0, i], zero-fill to 128-boundary.
__global__ __launch_bounds__(256) void softmax_causal(
    const float* __restrict__ scores, u16* __restrict__ P, long strideSb, long stridePb) {
  const int b = blockIdx.z;
  const int i = blockIdx.x;
  const float* srow = scores + (long)b * strideSb + (long)i * S_LEN;
  u16* prow = P + (long)b * stridePb + (long)i * S_LEN;
  const int W = ((i >> 7) + 1) << 7;  // multiple of 128
  const int tid = threadIdx.x;
  const int lane = tid & 63;
  const int wave = tid >> 6;

  f32x4 v[2];
  int nc = 0;
  float lmax = -1e30f;
  for (int j = tid * 4; j < W; j += 1024) {
    f32x4 x = *reinterpret_cast<const f32x4*>(srow + j);
#pragma unroll
    for (int q = 0; q < 4; q++) {
      x[q] = (j + q <= i) ? x[q] * 0.03125f : -1e30f;
      lmax = fmaxf(lmax, x[q]);
    }
    v[nc++] = x;
  }
#pragma unroll
  for (int off = 32; off; off >>= 1) lmax = fmaxf(lmax, __shfl_xor(lmax, off));
  __shared__ float redm[4], reds[4];
  if (lane == 0) redm[wave] = lmax;
  __syncthreads();
  const float m = fmaxf(fmaxf(redm[0], redm[1]), fmaxf(redm[2], redm[3]));

  float lsum = 0.f;
  int c = 0;
  for (int j = tid * 4; j < W; j += 1024, ++c) {
#pragma unroll
    for (int q = 0; q < 4; q++) {
      float p = __expf(v[c][q] - m);
      v[c][q] = p;
      lsum += p;
    }
  }
#pragma unroll
  for (int off = 32; off; off >>= 1) lsum += __shfl_xor(lsum, off);
  if (lane == 0) reds[wave] = lsum;
  __syncthreads();
  const float inv = 1.f / (reds[0] + reds[1] + reds[2] + reds[3]);

  c = 0;
  for (int j = tid * 4; j < W; j += 1024, ++c) {
    u16x4 o;
#pragma unroll
    for (int q = 0; q < 4; q++) o[q] = f2bf(v[c][q] * inv);
    *reinterpret_cast<u16x4*>(prow + j) = o;
  }
}

extern "C" void kernel_launch(void* const* d_in, const int* in_sizes, int n_in,
                              void* d_out, int out_size, void* d_ws, size_t ws_size,
                              hipStream_t stream) {
  const float* x = (const float*)d_in[0];
  const float* Wq = (const float*)d_in[1];
  const float* Wk = (const float*)d_in[2];
  const float* Wv = (const float*)d_in[3];
  float* out = (float*)d_out;

  const size_t SD = (size_t)S_LEN * D_DIM;  // 2,097,152
  const size_t SS = (size_t)S_LEN * S_LEN;  // 4,194,304
  const size_t DD = (size_t)D_DIM * D_DIM;

  size_t off = 0;
  char* ws = (char*)d_ws;
  auto alloc = [&](size_t bytes) -> char* {
    char* p = ws + off;
    off += (bytes + 255) & ~(size_t)255;
    return p;
  };
  u16* xb = (u16*)alloc(NBATCH * SD * 2);
  u16* Wqkvb = (u16*)alloc(3 * DD * 2);           // [Wq;Wk;Wv] rows, [3072,1024]
  u16* QKVt = (u16*)alloc(3 * NBATCH * SD * 2);   // Qb | Kb | Vt contiguous
  u16* Qb = QKVt;
  u16* Kb = QKVt + NBATCH * SD;
  u16* Vt = QKVt + 2 * NBATCH * SD;
  size_t need_full = off + ((NBATCH * SS * 4 + 255) & ~(size_t)255) +
                     ((NBATCH * SS * 2 + 255) & ~(size_t)255);
  const int nbpar = (ws_size >= need_full) ? NBATCH : 1;
  float* scores = (float*)alloc((size_t)nbpar * SS * 4);
  u16* P = (u16*)alloc((size_t)nbpar * SS * 2);

  // casts (weights go into the concatenated [3072,1024] buffer)
  cast_f32_bf16<<<2048, 256, 0, stream>>>(x, xb, (int)(NBATCH * SD));
  cast_f32_bf16<<<512, 256, 0, stream>>>(Wq, Wqkvb, (int)DD);
  cast_f32_bf16<<<512, 256, 0, stream>>>(Wk, Wqkvb + DD, (int)DD);
  cast_f32_bf16<<<512, 256, 0, stream>>>(Wv, Wqkvb + 2 * DD, (int)DD);

  // fused QKV projection: M = 8192, N = 3072, K = 1024
  dim3 gp((NBATCH * S_LEN) / BM, 3 * D_DIM / BN, 1);
  gemm_bt<MODE_QKV><<<gp, 256, 0, stream>>>(xb, Wqkvb, Qb, NBATCH * S_LEN, 3 * D_DIM, D_DIM,
                                            0, 0, 0, D_DIM);

  const int ntri = (S_LEN / BM) * (S_LEN / BM + 1) / 2;  // 136
  if (nbpar == NBATCH) {
    gemm_bt<MODE_SC><<<dim3(ntri, 1, NBATCH), 256, 0, stream>>>(
        Qb, Kb, scores, S_LEN, S_LEN, D_DIM, (long)SD, (long)SD, (long)SS, S_LEN);
    softmax_causal<<<dim3(S_LEN, 1, NBATCH), 256, 0, stream>>>(scores, P, (long)SS, (long)SS);
    gemm_bt<MODE_PV><<<dim3(S_LEN / BM, D_DIM / BN, NBATCH), 256, 0, stream>>>(
        P, Vt, out, S_LEN, D_DIM, S_LEN, (long)SS, (long)SD, (long)SD, D_DIM);
  } else {
    for (int b = 0; b < NBATCH; ++b) {
      gemm_bt<MODE_SC><<<dim3(ntri, 1, 1), 256, 0, stream>>>(
          Qb + b * SD, Kb + b * SD, scores, S_LEN, S_LEN, D_DIM, 0, 0, 0, S_LEN);
      softmax_causal<<<dim3(S_LEN, 1, 1), 256, 0, stream>>>(scores, P, 0, 0);
      gemm_bt<MODE_PV><<<dim3(S_LEN / BM, D_DIM / BN, 1), 256, 0, stream>>>(
          P, Vt + b * SD, out + b * SD, S_LEN, D_DIM, S_LEN, 0, 0, 0, D_DIM);
    }
  }
}